// Round 1
// baseline (567.467 us; speedup 1.0000x reference)
//
#include <hip/hip_runtime.h>
#include <math.h>

#define EPS 1e-7f
#define SCALE 0.17677669529663687f  // 32^-0.5

// ---------- weight transposes: Wt[k][w*128+j] = W_w[j][k] ----------
__global__ __launch_bounds__(256) void build_wt(
    const float* __restrict__ Wq, const float* __restrict__ Wk,
    const float* __restrict__ Wv, float* __restrict__ Wt) {
  int o = blockIdx.x * 256 + threadIdx.x;
  if (o >= 128 * 384) return;
  int i = o / 384;           // k index
  int rem = o - i * 384;
  int w = rem >> 7;          // which matrix
  int j = rem & 127;         // output column within matrix
  const float* W = (w == 0) ? Wq : (w == 1) ? Wk : Wv;
  Wt[o] = W[j * 128 + i];
}

__global__ __launch_bounds__(256) void build_wot(
    const float* __restrict__ Wo, float* __restrict__ Wot) {
  int o = blockIdx.x * 256 + threadIdx.x;
  if (o >= 128 * 128) return;
  int i = o >> 7;
  int j = o & 127;
  Wot[o] = Wo[j * 128 + i];
}

// ---------- log map at origin: x (N x 129) -> x_tan (N x 128) ----------
__global__ __launch_bounds__(128) void xtan_kernel(
    const float* __restrict__ x, float* __restrict__ xt, int N) {
  int n = blockIdx.x;
  int t = threadIdx.x;
  float xs = x[n * 129 + 1 + t];
  float ss = xs * xs;
#pragma unroll
  for (int o = 32; o >= 1; o >>= 1) ss += __shfl_xor(ss, o, 64);
  __shared__ float wred[2];
  if ((t & 63) == 0) wred[t >> 6] = ss;
  __syncthreads();
  float tot = wred[0] + wred[1];
  float norm = sqrtf(tot + EPS);
  float x0 = x[n * 129];
  float dist = acoshf(fmaxf(x0, 1.0f + EPS));
  xt[n * 128 + t] = (dist / norm) * xs;
}

// ---------- fp32 SGEMM: C(MxN) = A(Mx128) @ B(128xN) (+bias) ----------
// 128x128 tile, BK=32, 256 threads, 8x8 micro-tile per thread.
__global__ __launch_bounds__(256) void gemm_k128(
    const float* __restrict__ A, const float* __restrict__ B,
    float* __restrict__ C, const float* __restrict__ bias, int M, int N) {
  __shared__ float As[32][128];  // As[k][m]
  __shared__ float Bs[32][128];  // Bs[k][n]
  const int mbase = blockIdx.x * 128;
  const int nbase = blockIdx.y * 128;
  const int t = threadIdx.x;
  const int tx = t & 15;
  const int ty = t >> 4;
  float acc[8][8];
#pragma unroll
  for (int i = 0; i < 8; i++)
#pragma unroll
    for (int j = 0; j < 8; j++) acc[i][j] = 0.f;

  for (int k0 = 0; k0 < 128; k0 += 32) {
#pragma unroll
    for (int i = 0; i < 4; i++) {
      int idx = t + i * 256;
      int m = idx >> 3;
      int kf = (idx & 7) << 2;
      int grow = mbase + m;
      float4 v = make_float4(0.f, 0.f, 0.f, 0.f);
      if (grow < M) v = *reinterpret_cast<const float4*>(&A[(size_t)grow * 128 + k0 + kf]);
      As[kf + 0][m] = v.x;
      As[kf + 1][m] = v.y;
      As[kf + 2][m] = v.z;
      As[kf + 3][m] = v.w;
    }
#pragma unroll
    for (int i = 0; i < 4; i++) {
      int idx = t + i * 256;
      int kr = idx >> 5;
      int nc = (idx & 31) << 2;
      *reinterpret_cast<float4*>(&Bs[kr][nc]) =
          *reinterpret_cast<const float4*>(&B[(size_t)(k0 + kr) * N + nbase + nc]);
    }
    __syncthreads();
#pragma unroll
    for (int k = 0; k < 32; k++) {
      float a[8], b[8];
      *reinterpret_cast<float4*>(&a[0]) = *reinterpret_cast<const float4*>(&As[k][ty * 8]);
      *reinterpret_cast<float4*>(&a[4]) = *reinterpret_cast<const float4*>(&As[k][ty * 8 + 4]);
      *reinterpret_cast<float4*>(&b[0]) = *reinterpret_cast<const float4*>(&Bs[k][tx * 8]);
      *reinterpret_cast<float4*>(&b[4]) = *reinterpret_cast<const float4*>(&Bs[k][tx * 8 + 4]);
#pragma unroll
      for (int i = 0; i < 8; i++)
#pragma unroll
        for (int j = 0; j < 8; j++) acc[i][j] = fmaf(a[i], b[j], acc[i][j]);
    }
    __syncthreads();
  }
#pragma unroll
  for (int i = 0; i < 8; i++) {
    int m = mbase + ty * 8 + i;
    if (m < M) {
#pragma unroll
      for (int jb = 0; jb < 2; jb++) {
        int n = nbase + tx * 8 + jb * 4;
        float4 v;
        v.x = acc[i][jb * 4 + 0];
        v.y = acc[i][jb * 4 + 1];
        v.z = acc[i][jb * 4 + 2];
        v.w = acc[i][jb * 4 + 3];
        if (bias) {
          v.x += bias[n + 0];
          v.y += bias[n + 1];
          v.z += bias[n + 2];
          v.w += bias[n + 3];
        }
        *reinterpret_cast<float4*>(&C[(size_t)m * N + n]) = v;
      }
    }
  }
}

// ---------- CSR build ----------
__global__ __launch_bounds__(256) void count_kernel(
    const int* __restrict__ col, int* __restrict__ cnt, int E) {
  int e = blockIdx.x * 256 + threadIdx.x;
  if (e < E) atomicAdd(&cnt[col[e]], 1);
}

__global__ __launch_bounds__(1024) void scan_kernel(
    const int* __restrict__ cnt, int* __restrict__ offs, int* __restrict__ cur, int N) {
  __shared__ int wsum[17];
  int t = threadIdx.x;
  int lane = t & 63;
  int w = t >> 6;
  int carry = 0;
  for (int base = 0; base < N; base += 1024) {
    int i = base + t;
    int v = (i < N) ? cnt[i] : 0;
    int inc = v;
#pragma unroll
    for (int d = 1; d < 64; d <<= 1) {
      int u = __shfl_up(inc, d, 64);
      if (lane >= d) inc += u;
    }
    if (lane == 63) wsum[w] = inc;
    __syncthreads();
    if (t < 16) {
      int sv = wsum[t];
      int sinc = sv;
#pragma unroll
      for (int d = 1; d < 16; d <<= 1) {
        int u = __shfl_up(sinc, d, 64);
        if (t >= d) sinc += u;
      }
      wsum[t] = sinc - sv;  // exclusive wave prefix
      if (t == 15) wsum[16] = sinc;
    }
    __syncthreads();
    int excl = carry + wsum[w] + inc - v;
    if (i < N) {
      offs[i] = excl;
      cur[i] = excl;
    }
    carry += wsum[16];
    __syncthreads();
  }
  if (t == 0) offs[N] = carry;
}

__global__ __launch_bounds__(256) void scatter_kernel(
    const int* __restrict__ col, int* __restrict__ cur, int* __restrict__ perm, int E) {
  int e = blockIdx.x * 256 + threadIdx.x;
  if (e < E) {
    int pos = atomicAdd(&cur[col[e]], 1);
    perm[pos] = e;
  }
}

// ---------- node-centric graph attention (online softmax, no atomics) ----------
// block = 128 threads = node n; thread t: head h=t>>5, dim d=t&31.
__global__ __launch_bounds__(128) void attn_kernel(
    const float* __restrict__ QKV, const int* __restrict__ row,
    const int* __restrict__ perm, const int* __restrict__ offs,
    float* __restrict__ agg, int N) {
  int n = blockIdx.x;
  int t = threadIdx.x;
  float q = QKV[(size_t)n * 384 + t];
  int s0 = offs[n], s1 = offs[n + 1];
  float m = -INFINITY, l = 0.f, acc = 0.f;
  for (int i = s0; i < s1; i++) {
    int e = perm[i];
    int r = row[e];
    const float* kv = QKV + (size_t)r * 384;
    float kval = kv[128 + t];
    float vval = kv[256 + t];
    float p = q * kval;
    p += __shfl_xor(p, 16, 32);
    p += __shfl_xor(p, 8, 32);
    p += __shfl_xor(p, 4, 32);
    p += __shfl_xor(p, 2, 32);
    p += __shfl_xor(p, 1, 32);
    float s = p * SCALE;
    float mn = fmaxf(m, s);
    float alpha = expf(m - mn);  // first iter: exp(-inf)=0
    float pe = expf(s - mn);
    l = l * alpha + pe;
    acc = acc * alpha + pe * vval;
    m = mn;
  }
  agg[(size_t)n * 128 + t] = (l > 0.f) ? acc / l : 0.f;
}

// ---------- exp map at origin: vlin (N x 128) -> out (N x 129) ----------
__global__ __launch_bounds__(128) void expmap_kernel(
    const float* __restrict__ vlin, float* __restrict__ out, int N) {
  int n = blockIdx.x;
  int t = threadIdx.x;
  float v = vlin[(size_t)n * 128 + t];
  float ss = v * v;
#pragma unroll
  for (int o = 32; o >= 1; o >>= 1) ss += __shfl_xor(ss, o, 64);
  __shared__ float wred[2];
  if ((t & 63) == 0) wred[t >> 6] = ss;
  __syncthreads();
  float tot = wred[0] + wred[1];
  float r = sqrtf(tot + EPS);
  float s = sinhf(r) / r;
  out[(size_t)n * 129 + 1 + t] = s * v;
  if (t == 0) out[(size_t)n * 129] = coshf(r);
}

extern "C" void kernel_launch(void* const* d_in, const int* in_sizes, int n_in,
                              void* d_out, int out_size, void* d_ws, size_t ws_size,
                              hipStream_t stream) {
  const float* x = (const float*)d_in[0];
  const int* ei = (const int*)d_in[1];
  const float* Wq = (const float*)d_in[2];
  const float* Wk = (const float*)d_in[3];
  const float* Wv = (const float*)d_in[4];
  const float* Wo = (const float*)d_in[5];
  const float* bo = (const float*)d_in[6];
  float* out = (float*)d_out;

  const int N = in_sizes[0] / 129;
  const int E = in_sizes[1] / 2;
  const int* row = ei;       // edge_index[0]
  const int* col = ei + E;   // edge_index[1]

  char* ws = (char*)d_ws;
  size_t off = 0;
  auto alloc = [&](size_t bytes) -> void* {
    off = (off + 255) & ~(size_t)255;
    void* p = ws + off;
    off += bytes;
    return p;
  };
  float* xtan = (float*)alloc((size_t)N * 128 * 4);  // reused as agg after QKV GEMM
  float* qkv  = (float*)alloc((size_t)N * 384 * 4);  // reused as out_lin after attention
  int* perm   = (int*)alloc((size_t)E * 4);
  float* Wt   = (float*)alloc(128 * 384 * 4);
  float* Wot  = (float*)alloc(128 * 128 * 4);
  int* cnt    = (int*)alloc((size_t)(N + 1) * 4);
  int* offs   = (int*)alloc((size_t)(N + 1) * 4);
  int* cur    = (int*)alloc((size_t)N * 4);

  hipMemsetAsync(cnt, 0, (size_t)(N + 1) * 4, stream);
  build_wt<<<192, 256, 0, stream>>>(Wq, Wk, Wv, Wt);
  build_wot<<<64, 256, 0, stream>>>(Wo, Wot);
  xtan_kernel<<<N, 128, 0, stream>>>(x, xtan, N);
  gemm_k128<<<dim3((N + 127) / 128, 3), 256, 0, stream>>>(xtan, Wt, qkv, nullptr, N, 384);
  count_kernel<<<(E + 255) / 256, 256, 0, stream>>>(col, cnt, E);
  scan_kernel<<<1, 1024, 0, stream>>>(cnt, offs, cur, N);
  scatter_kernel<<<(E + 255) / 256, 256, 0, stream>>>(col, cur, perm, E);
  attn_kernel<<<N, 128, 0, stream>>>(qkv, row, perm, offs, xtan, N);
  gemm_k128<<<dim3((N + 127) / 128, 1), 256, 0, stream>>>(xtan, Wot, qkv, bo, N, 128);
  expmap_kernel<<<N, 128, 0, stream>>>(qkv, out, N);
}

// Round 2
// 454.246 us; speedup vs baseline: 1.2493x; 1.2493x over previous
//
#include <hip/hip_runtime.h>
#include <math.h>

#define EPS 1e-7f
#define SCALE 0.17677669529663687f  // 32^-0.5

typedef _Float16 half2v __attribute__((ext_vector_type(2)));

// ---------- weight transposes: Wt[k][w*128+j] = W_w[j][k] ----------
__global__ __launch_bounds__(256) void build_wt(
    const float* __restrict__ Wq, const float* __restrict__ Wk,
    const float* __restrict__ Wv, float* __restrict__ Wt) {
  int o = blockIdx.x * 256 + threadIdx.x;
  if (o >= 128 * 384) return;
  int i = o / 384;           // k index
  int rem = o - i * 384;
  int w = rem >> 7;          // which matrix
  int j = rem & 127;         // output column within matrix
  const float* W = (w == 0) ? Wq : (w == 1) ? Wk : Wv;
  Wt[o] = W[j * 128 + i];
}

__global__ __launch_bounds__(256) void build_wot(
    const float* __restrict__ Wo, float* __restrict__ Wot) {
  int o = blockIdx.x * 256 + threadIdx.x;
  if (o >= 128 * 128) return;
  int i = o >> 7;
  int j = o & 127;
  Wot[o] = Wo[j * 128 + i];
}

// ---------- log map at origin: x (N x 129) -> x_tan (N x 128) ----------
__global__ __launch_bounds__(128) void xtan_kernel(
    const float* __restrict__ x, float* __restrict__ xt, int N) {
  int n = blockIdx.x;
  int t = threadIdx.x;
  float xs = x[n * 129 + 1 + t];
  float ss = xs * xs;
#pragma unroll
  for (int o = 32; o >= 1; o >>= 1) ss += __shfl_xor(ss, o, 64);
  __shared__ float wred[2];
  if ((t & 63) == 0) wred[t >> 6] = ss;
  __syncthreads();
  float tot = wred[0] + wred[1];
  float norm = sqrtf(tot + EPS);
  float x0 = x[n * 129];
  float dist = acoshf(fmaxf(x0, 1.0f + EPS));
  xt[n * 128 + t] = (dist / norm) * xs;
}

// ---------- fp32 SGEMM: C(MxN) = A(Mx128) @ B(128xN) (+bias) ----------
__global__ __launch_bounds__(256) void gemm_k128(
    const float* __restrict__ A, const float* __restrict__ B,
    float* __restrict__ C, const float* __restrict__ bias, int M, int N) {
  __shared__ float As[32][128];  // As[k][m]
  __shared__ float Bs[32][128];  // Bs[k][n]
  const int mbase = blockIdx.x * 128;
  const int nbase = blockIdx.y * 128;
  const int t = threadIdx.x;
  const int tx = t & 15;
  const int ty = t >> 4;
  float acc[8][8];
#pragma unroll
  for (int i = 0; i < 8; i++)
#pragma unroll
    for (int j = 0; j < 8; j++) acc[i][j] = 0.f;

  for (int k0 = 0; k0 < 128; k0 += 32) {
#pragma unroll
    for (int i = 0; i < 4; i++) {
      int idx = t + i * 256;
      int m = idx >> 3;
      int kf = (idx & 7) << 2;
      int grow = mbase + m;
      float4 v = make_float4(0.f, 0.f, 0.f, 0.f);
      if (grow < M) v = *reinterpret_cast<const float4*>(&A[(size_t)grow * 128 + k0 + kf]);
      As[kf + 0][m] = v.x;
      As[kf + 1][m] = v.y;
      As[kf + 2][m] = v.z;
      As[kf + 3][m] = v.w;
    }
#pragma unroll
    for (int i = 0; i < 4; i++) {
      int idx = t + i * 256;
      int kr = idx >> 5;
      int nc = (idx & 31) << 2;
      *reinterpret_cast<float4*>(&Bs[kr][nc]) =
          *reinterpret_cast<const float4*>(&B[(size_t)(k0 + kr) * N + nbase + nc]);
    }
    __syncthreads();
#pragma unroll
    for (int k = 0; k < 32; k++) {
      float a[8], b[8];
      *reinterpret_cast<float4*>(&a[0]) = *reinterpret_cast<const float4*>(&As[k][ty * 8]);
      *reinterpret_cast<float4*>(&a[4]) = *reinterpret_cast<const float4*>(&As[k][ty * 8 + 4]);
      *reinterpret_cast<float4*>(&b[0]) = *reinterpret_cast<const float4*>(&Bs[k][tx * 8]);
      *reinterpret_cast<float4*>(&b[4]) = *reinterpret_cast<const float4*>(&Bs[k][tx * 8 + 4]);
#pragma unroll
      for (int i = 0; i < 8; i++)
#pragma unroll
        for (int j = 0; j < 8; j++) acc[i][j] = fmaf(a[i], b[j], acc[i][j]);
    }
    __syncthreads();
  }
#pragma unroll
  for (int i = 0; i < 8; i++) {
    int m = mbase + ty * 8 + i;
    if (m < M) {
#pragma unroll
      for (int jb = 0; jb < 2; jb++) {
        int n = nbase + tx * 8 + jb * 4;
        float4 v;
        v.x = acc[i][jb * 4 + 0];
        v.y = acc[i][jb * 4 + 1];
        v.z = acc[i][jb * 4 + 2];
        v.w = acc[i][jb * 4 + 3];
        if (bias) {
          v.x += bias[n + 0];
          v.y += bias[n + 1];
          v.z += bias[n + 2];
          v.w += bias[n + 3];
        }
        *reinterpret_cast<float4*>(&C[(size_t)m * N + n]) = v;
      }
    }
  }
}

// ---------- convert K,V columns of QKV (fp32) to fp16 KV buffer ----------
// KV layout per node: 128 half2 = [K half2 0..63 | V half2 64..127]
__global__ __launch_bounds__(64) void kvhalf_kernel(
    const float* __restrict__ qkv, half2v* __restrict__ kvh, int N) {
  int n = blockIdx.x;
  int t = threadIdx.x;
  float4 v = *reinterpret_cast<const float4*>(&qkv[(size_t)n * 384 + 128 + t * 4]);
  half2v a, b;
  a.x = (_Float16)v.x; a.y = (_Float16)v.y;
  b.x = (_Float16)v.z; b.y = (_Float16)v.w;
  half2v* dst = kvh + (size_t)n * 128 + t * 2;
  dst[0] = a;
  dst[1] = b;
}

// ---------- CSR build ----------
__global__ __launch_bounds__(256) void count_kernel(
    const int* __restrict__ col, int* __restrict__ cnt, int E) {
  int e = blockIdx.x * 256 + threadIdx.x;
  if (e < E) atomicAdd(&cnt[col[e]], 1);
}

__global__ __launch_bounds__(1024) void scan_kernel(
    const int* __restrict__ cnt, int* __restrict__ offs, int* __restrict__ cur, int N) {
  __shared__ int wsum[17];
  int t = threadIdx.x;
  int lane = t & 63;
  int w = t >> 6;
  int carry = 0;
  for (int base = 0; base < N; base += 1024) {
    int i = base + t;
    int v = (i < N) ? cnt[i] : 0;
    int inc = v;
#pragma unroll
    for (int d = 1; d < 64; d <<= 1) {
      int u = __shfl_up(inc, d, 64);
      if (lane >= d) inc += u;
    }
    if (lane == 63) wsum[w] = inc;
    __syncthreads();
    if (t < 16) {
      int sv = wsum[t];
      int sinc = sv;
#pragma unroll
      for (int d = 1; d < 16; d <<= 1) {
        int u = __shfl_up(sinc, d, 64);
        if (t >= d) sinc += u;
      }
      wsum[t] = sinc - sv;  // exclusive wave prefix
      if (t == 15) wsum[16] = sinc;
    }
    __syncthreads();
    int excl = carry + wsum[w] + inc - v;
    if (i < N) {
      offs[i] = excl;
      cur[i] = excl;
    }
    carry += wsum[16];
    __syncthreads();
  }
  if (t == 0) offs[N] = carry;
}

// stores SOURCE node id directly (saves one indirection in attn)
__global__ __launch_bounds__(256) void scatter_kernel(
    const int* __restrict__ col, const int* __restrict__ row,
    int* __restrict__ cur, int* __restrict__ rperm, int E) {
  int e = blockIdx.x * 256 + threadIdx.x;
  if (e < E) {
    int pos = atomicAdd(&cur[col[e]], 1);
    rperm[pos] = row[e];
  }
}

// ---------- node-centric graph attention, no-max softmax (scores bounded) ----
// 1 wave per node: lane = h*16 + di, each lane owns 2 dims (half2).
__global__ __launch_bounds__(256) void attn_kernel(
    const float* __restrict__ QKV,   // N x 384 fp32 (Q = cols 0..127)
    const half2v* __restrict__ KV,   // N x 128 half2
    const int* __restrict__ rperm, const int* __restrict__ offs,
    float* __restrict__ agg, int N) {
  int node = blockIdx.x * 4 + (threadIdx.x >> 6);
  if (node >= N) return;
  int lane = threadIdx.x & 63;
  int hd = lane;  // h*16 + di
  float2 q = reinterpret_cast<const float2*>(QKV)[(size_t)node * 192 + hd];
  int s0 = offs[node], s1 = offs[node + 1];
  float l = 0.f, ax = 0.f, ay = 0.f;
  int i = s0;
  for (; i + 2 <= s1; i += 2) {
    int r0 = rperm[i];
    int r1 = rperm[i + 1];
    const half2v* b0 = KV + (size_t)r0 * 128 + hd;
    const half2v* b1 = KV + (size_t)r1 * 128 + hd;
    half2v k0 = b0[0], v0 = b0[64];
    half2v k1 = b1[0], v1 = b1[64];
    float p0 = fmaf(q.x, (float)k0.x, q.y * (float)k0.y);
    float p1 = fmaf(q.x, (float)k1.x, q.y * (float)k1.y);
#pragma unroll
    for (int o = 8; o >= 1; o >>= 1) {
      p0 += __shfl_xor(p0, o, 16);
      p1 += __shfl_xor(p1, o, 16);
    }
    float pe0 = __expf(p0 * SCALE);
    float pe1 = __expf(p1 * SCALE);
    l += pe0 + pe1;
    ax = fmaf(pe0, (float)v0.x, ax);
    ax = fmaf(pe1, (float)v1.x, ax);
    ay = fmaf(pe0, (float)v0.y, ay);
    ay = fmaf(pe1, (float)v1.y, ay);
  }
  if (i < s1) {
    int r0 = rperm[i];
    const half2v* b0 = KV + (size_t)r0 * 128 + hd;
    half2v k0 = b0[0], v0 = b0[64];
    float p0 = fmaf(q.x, (float)k0.x, q.y * (float)k0.y);
#pragma unroll
    for (int o = 8; o >= 1; o >>= 1) p0 += __shfl_xor(p0, o, 16);
    float pe0 = __expf(p0 * SCALE);
    l += pe0;
    ax = fmaf(pe0, (float)v0.x, ax);
    ay = fmaf(pe0, (float)v0.y, ay);
  }
  float inv = (l > 0.f) ? 1.0f / l : 0.f;
  float2 o2;
  o2.x = ax * inv;
  o2.y = ay * inv;
  reinterpret_cast<float2*>(agg)[(size_t)node * 64 + hd] = o2;
}

// ---------- exp map at origin: vlin (N x 128) -> out (N x 129) ----------
__global__ __launch_bounds__(128) void expmap_kernel(
    const float* __restrict__ vlin, float* __restrict__ out, int N) {
  int n = blockIdx.x;
  int t = threadIdx.x;
  float v = vlin[(size_t)n * 128 + t];
  float ss = v * v;
#pragma unroll
  for (int o = 32; o >= 1; o >>= 1) ss += __shfl_xor(ss, o, 64);
  __shared__ float wred[2];
  if ((t & 63) == 0) wred[t >> 6] = ss;
  __syncthreads();
  float tot = wred[0] + wred[1];
  float r = sqrtf(tot + EPS);
  float s = sinhf(r) / r;
  out[(size_t)n * 129 + 1 + t] = s * v;
  if (t == 0) out[(size_t)n * 129] = coshf(r);
}

extern "C" void kernel_launch(void* const* d_in, const int* in_sizes, int n_in,
                              void* d_out, int out_size, void* d_ws, size_t ws_size,
                              hipStream_t stream) {
  const float* x = (const float*)d_in[0];
  const int* ei = (const int*)d_in[1];
  const float* Wq = (const float*)d_in[2];
  const float* Wk = (const float*)d_in[3];
  const float* Wv = (const float*)d_in[4];
  const float* Wo = (const float*)d_in[5];
  const float* bo = (const float*)d_in[6];
  float* out = (float*)d_out;

  const int N = in_sizes[0] / 129;
  const int E = in_sizes[1] / 2;
  const int* row = ei;       // edge_index[0]
  const int* col = ei + E;   // edge_index[1]

  char* ws = (char*)d_ws;
  size_t off = 0;
  auto alloc = [&](size_t bytes) -> void* {
    off = (off + 255) & ~(size_t)255;
    void* p = ws + off;
    off += bytes;
    return p;
  };
  float* xtan  = (float*)alloc((size_t)N * 128 * 4);  // reused as agg after QKV GEMM
  float* qkv   = (float*)alloc((size_t)N * 384 * 4);  // reused as out_lin after attention
  half2v* kvh  = (half2v*)alloc((size_t)N * 256 * 2);
  int* rperm   = (int*)alloc((size_t)E * 4);
  float* Wt    = (float*)alloc(128 * 384 * 4);
  float* Wot   = (float*)alloc(128 * 128 * 4);
  int* cnt     = (int*)alloc((size_t)(N + 1) * 4);
  int* offs    = (int*)alloc((size_t)(N + 1) * 4);
  int* cur     = (int*)alloc((size_t)N * 4);

  hipMemsetAsync(cnt, 0, (size_t)(N + 1) * 4, stream);
  build_wt<<<192, 256, 0, stream>>>(Wq, Wk, Wv, Wt);
  build_wot<<<64, 256, 0, stream>>>(Wo, Wot);
  xtan_kernel<<<N, 128, 0, stream>>>(x, xtan, N);
  gemm_k128<<<dim3((N + 127) / 128, 3), 256, 0, stream>>>(xtan, Wt, qkv, nullptr, N, 384);
  kvhalf_kernel<<<N, 64, 0, stream>>>(qkv, kvh, N);
  count_kernel<<<(E + 255) / 256, 256, 0, stream>>>(col, cnt, E);
  scan_kernel<<<1, 1024, 0, stream>>>(cnt, offs, cur, N);
  scatter_kernel<<<(E + 255) / 256, 256, 0, stream>>>(col, row, cur, rperm, E);
  attn_kernel<<<(N + 3) / 4, 256, 0, stream>>>(qkv, kvh, rperm, offs, xtan, N);
  gemm_k128<<<dim3((N + 127) / 128, 1), 256, 0, stream>>>(xtan, Wot, qkv, bo, N, 128);
  expmap_kernel<<<N, 128, 0, stream>>>(qkv, out, N);
}

// Round 3
// 355.998 us; speedup vs baseline: 1.5940x; 1.2760x over previous
//
#include <hip/hip_runtime.h>
#include <math.h>

#define EPS 1e-7f
#define SCALE 0.17677669529663687f  // 32^-0.5

typedef _Float16 half2v __attribute__((ext_vector_type(2)));
typedef _Float16 f16x8 __attribute__((ext_vector_type(8)));
typedef float f32x4 __attribute__((ext_vector_type(4)));

__device__ __forceinline__ void gload16(const void* g, void* l) {
  __builtin_amdgcn_global_load_lds(
      (const __attribute__((address_space(1))) unsigned int*)g,
      (__attribute__((address_space(3))) unsigned int*)l, 16, 0, 0);
}

// ---------- weight convert: Wcomb (384x128 f16) = [Wq;Wk;Wv] rows=out col ----
__global__ __launch_bounds__(256) void build_wcomb(
    const float* __restrict__ Wq, const float* __restrict__ Wk,
    const float* __restrict__ Wv, _Float16* __restrict__ Wc) {
  int o = blockIdx.x * 256 + threadIdx.x;
  if (o >= 384 * 128) return;
  int j = o >> 7;
  int i = o & 127;
  const float* W = (j < 128) ? Wq : (j < 256) ? Wk : Wv;
  Wc[o] = (_Float16)W[(j & 127) * 128 + i];
}

__global__ __launch_bounds__(256) void build_wo16(
    const float* __restrict__ Wo, _Float16* __restrict__ Wof) {
  int o = blockIdx.x * 256 + threadIdx.x;
  if (o >= 128 * 128) return;
  Wof[o] = (_Float16)Wo[o];
}

// ---------- log map at origin: x (N x 129) -> x_tan (N x 128) f16 ----------
__global__ __launch_bounds__(128) void xtan_kernel(
    const float* __restrict__ x, _Float16* __restrict__ xt, int N) {
  int n = blockIdx.x;
  int t = threadIdx.x;
  float xs = x[n * 129 + 1 + t];
  float ss = xs * xs;
#pragma unroll
  for (int o = 32; o >= 1; o >>= 1) ss += __shfl_xor(ss, o, 64);
  __shared__ float wred[2];
  if ((t & 63) == 0) wred[t >> 6] = ss;
  __syncthreads();
  float tot = wred[0] + wred[1];
  float norm = sqrtf(tot + EPS);
  float x0 = x[n * 129];
  float dist = acoshf(fmaxf(x0, 1.0f + EPS));
  xt[n * 128 + t] = (_Float16)((dist / norm) * xs);
}

// ---------- f16 MFMA GEMM: C = A(Mx128) @ B^T, B rows = output cols ----------
// block: 256 thr (4 waves, 2x2), tile 64(M) x 128(N) per chunk, K=128 unrolled.
// LDS chunks (16B) XOR-swizzled on the SOURCE index so ds_read_b128 is
// conflict-free while global_load_lds keeps its lane-ordered destination.
template <int NCHUNKS, bool F16OUT>
__global__ __launch_bounds__(256, 3) void gemm_mfma(
    const _Float16* __restrict__ A,   // M x 128
    const _Float16* __restrict__ B,   // (NCHUNKS*128) x 128
    void* __restrict__ C,             // f16 Mx(NCHUNKS*128) or f32 Mx128
    const float* __restrict__ bias, int M) {
  __shared__ _Float16 As[64 * 128];
  __shared__ _Float16 Bs[128 * 128];
  const int tid = threadIdx.x;
  const int wave = tid >> 6;
  const int lane = tid & 63;
  const int wm = wave >> 1, wn = wave & 1;
  const int lrow = lane & 15, q = lane >> 4;
  const int m0 = blockIdx.x * 64;

  // stage A once: 1024 16B chunks; slot p holds logical (m = p>>4, kc = (p&15)^(m&15))
#pragma unroll
  for (int j = 0; j < 4; j++) {
    int slot0 = (j * 4 + wave) * 64;
    int p = slot0 + lane;
    int m = p >> 4;
    int kcl = (p & 15) ^ (m & 15);
    int msrc = m0 + m;
    if (msrc > M - 1) msrc = M - 1;
    gload16(A + (size_t)msrc * 128 + kcl * 8, (char*)As + (size_t)slot0 * 16);
  }

  for (int c = 0; c < NCHUNKS; c++) {
    // stage B chunk: 2048 chunks
#pragma unroll
    for (int j = 0; j < 8; j++) {
      int slot0 = (j * 4 + wave) * 64;
      int p = slot0 + lane;
      int n = p >> 4;
      int kcl = (p & 15) ^ (n & 15);
      gload16(B + ((size_t)(c * 128 + n)) * 128 + kcl * 8, (char*)Bs + (size_t)slot0 * 16);
    }
    __syncthreads();  // drains vmcnt -> LDS valid

    f32x4 acc[2][4];
#pragma unroll
    for (int mt = 0; mt < 2; mt++)
#pragma unroll
      for (int nt = 0; nt < 4; nt++) acc[mt][nt] = (f32x4)0.f;

    const f16x8* Av = (const f16x8*)As;
    const f16x8* Bv = (const f16x8*)Bs;
#pragma unroll
    for (int s = 0; s < 4; s++) {
      int kc = s * 4 + q;
      f16x8 af[2], bf[4];
#pragma unroll
      for (int mt = 0; mt < 2; mt++) {
        int m = wm * 32 + mt * 16 + lrow;
        af[mt] = Av[m * 16 + (kc ^ (m & 15))];
      }
#pragma unroll
      for (int nt = 0; nt < 4; nt++) {
        int n = wn * 64 + nt * 16 + lrow;
        bf[nt] = Bv[n * 16 + (kc ^ (n & 15))];
      }
#pragma unroll
      for (int mt = 0; mt < 2; mt++)
#pragma unroll
        for (int nt = 0; nt < 4; nt++)
          acc[mt][nt] = __builtin_amdgcn_mfma_f32_16x16x32_f16(af[mt], bf[nt], acc[mt][nt], 0, 0, 0);
    }

    // epilogue: D lane layout col=lane&15, row=q*4+reg
#pragma unroll
    for (int mt = 0; mt < 2; mt++) {
#pragma unroll
      for (int reg = 0; reg < 4; reg++) {
        int rg = m0 + wm * 32 + mt * 16 + q * 4 + reg;
        if (rg < M) {
#pragma unroll
          for (int nt = 0; nt < 4; nt++) {
            int cl = wn * 64 + nt * 16 + lrow;
            float v = acc[mt][nt][reg];
            if (F16OUT) {
              ((_Float16*)C)[(size_t)rg * (NCHUNKS * 128) + c * 128 + cl] = (_Float16)v;
            } else {
              ((float*)C)[(size_t)rg * 128 + cl] = v + bias[cl];
            }
          }
        }
      }
    }
    if (c + 1 < NCHUNKS) __syncthreads();  // protect Bs before restage
  }
}

// ---------- CSR build ----------
__global__ __launch_bounds__(256) void count_kernel(
    const int* __restrict__ col, int* __restrict__ cnt, int E) {
  int e = blockIdx.x * 256 + threadIdx.x;
  if (e < E) atomicAdd(&cnt[col[e]], 1);
}

__global__ __launch_bounds__(1024) void scan_kernel(
    const int* __restrict__ cnt, int* __restrict__ offs, int* __restrict__ cur, int N) {
  __shared__ int wsum[17];
  int t = threadIdx.x;
  int lane = t & 63;
  int w = t >> 6;
  int carry = 0;
  for (int base = 0; base < N; base += 1024) {
    int i = base + t;
    int v = (i < N) ? cnt[i] : 0;
    int inc = v;
#pragma unroll
    for (int d = 1; d < 64; d <<= 1) {
      int u = __shfl_up(inc, d, 64);
      if (lane >= d) inc += u;
    }
    if (lane == 63) wsum[w] = inc;
    __syncthreads();
    if (t < 16) {
      int sv = wsum[t];
      int sinc = sv;
#pragma unroll
      for (int d = 1; d < 16; d <<= 1) {
        int u = __shfl_up(sinc, d, 64);
        if (t >= d) sinc += u;
      }
      wsum[t] = sinc - sv;  // exclusive wave prefix
      if (t == 15) wsum[16] = sinc;
    }
    __syncthreads();
    int excl = carry + wsum[w] + inc - v;
    if (i < N) {
      offs[i] = excl;
      cur[i] = excl;
    }
    carry += wsum[16];
    __syncthreads();
  }
  if (t == 0) offs[N] = carry;
}

__global__ __launch_bounds__(256) void scatter_kernel(
    const int* __restrict__ col, const int* __restrict__ row,
    int* __restrict__ cur, int* __restrict__ rperm, int E) {
  int e = blockIdx.x * 256 + threadIdx.x;
  if (e < E) {
    int pos = atomicAdd(&cur[col[e]], 1);
    rperm[pos] = row[e];
  }
}

// ---------- node-centric graph attention, no-max softmax (scores bounded) ----
// 1 wave per node: lane = h*16 + di, each lane owns 2 dims (half2).
__global__ __launch_bounds__(256) void attn_kernel(
    const half2v* __restrict__ QKV,  // N x 192 half2 (Q|K|V)
    const int* __restrict__ rperm, const int* __restrict__ offs,
    half2v* __restrict__ agg, int N) {
  int node = blockIdx.x * 4 + (threadIdx.x >> 6);
  if (node >= N) return;
  int hd = threadIdx.x & 63;
  half2v qh = QKV[(size_t)node * 192 + hd];
  float qx = (float)qh.x, qy = (float)qh.y;
  int s0 = offs[node], s1 = offs[node + 1];
  float l = 0.f, ax = 0.f, ay = 0.f;
  int i = s0;
  for (; i + 2 <= s1; i += 2) {
    int r0 = rperm[i];
    int r1 = rperm[i + 1];
    const half2v* b0 = QKV + (size_t)r0 * 192 + 64 + hd;
    const half2v* b1 = QKV + (size_t)r1 * 192 + 64 + hd;
    half2v k0 = b0[0], v0 = b0[64];
    half2v k1 = b1[0], v1 = b1[64];
    float p0 = fmaf(qx, (float)k0.x, qy * (float)k0.y);
    float p1 = fmaf(qx, (float)k1.x, qy * (float)k1.y);
#pragma unroll
    for (int o = 8; o >= 1; o >>= 1) {
      p0 += __shfl_xor(p0, o, 16);
      p1 += __shfl_xor(p1, o, 16);
    }
    float pe0 = __expf(p0 * SCALE);
    float pe1 = __expf(p1 * SCALE);
    l += pe0 + pe1;
    ax = fmaf(pe0, (float)v0.x, ax);
    ax = fmaf(pe1, (float)v1.x, ax);
    ay = fmaf(pe0, (float)v0.y, ay);
    ay = fmaf(pe1, (float)v1.y, ay);
  }
  if (i < s1) {
    int r0 = rperm[i];
    const half2v* b0 = QKV + (size_t)r0 * 192 + 64 + hd;
    half2v k0 = b0[0], v0 = b0[64];
    float p0 = fmaf(qx, (float)k0.x, qy * (float)k0.y);
#pragma unroll
    for (int o = 8; o >= 1; o >>= 1) p0 += __shfl_xor(p0, o, 16);
    float pe0 = __expf(p0 * SCALE);
    l += pe0;
    ax = fmaf(pe0, (float)v0.x, ax);
    ay = fmaf(pe0, (float)v0.y, ay);
  }
  float inv = (l > 0.f) ? 1.0f / l : 0.f;
  half2v o2;
  o2.x = (_Float16)(ax * inv);
  o2.y = (_Float16)(ay * inv);
  agg[(size_t)node * 64 + hd] = o2;
}

// ---------- exp map at origin: vlin (N x 128) -> out (N x 129) ----------
__global__ __launch_bounds__(128) void expmap_kernel(
    const float* __restrict__ vlin, float* __restrict__ out, int N) {
  int n = blockIdx.x;
  int t = threadIdx.x;
  float v = vlin[(size_t)n * 128 + t];
  float ss = v * v;
#pragma unroll
  for (int o = 32; o >= 1; o >>= 1) ss += __shfl_xor(ss, o, 64);
  __shared__ float wred[2];
  if ((t & 63) == 0) wred[t >> 6] = ss;
  __syncthreads();
  float tot = wred[0] + wred[1];
  float r = sqrtf(tot + EPS);
  float s = sinhf(r) / r;
  out[(size_t)n * 129 + 1 + t] = s * v;
  if (t == 0) out[(size_t)n * 129] = coshf(r);
}

extern "C" void kernel_launch(void* const* d_in, const int* in_sizes, int n_in,
                              void* d_out, int out_size, void* d_ws, size_t ws_size,
                              hipStream_t stream) {
  const float* x = (const float*)d_in[0];
  const int* ei = (const int*)d_in[1];
  const float* Wq = (const float*)d_in[2];
  const float* Wk = (const float*)d_in[3];
  const float* Wv = (const float*)d_in[4];
  const float* Wo = (const float*)d_in[5];
  const float* bo = (const float*)d_in[6];
  float* out = (float*)d_out;

  const int N = in_sizes[0] / 129;
  const int E = in_sizes[1] / 2;
  const int* row = ei;       // edge_index[0]
  const int* col = ei + E;   // edge_index[1]

  char* ws = (char*)d_ws;
  size_t off = 0;
  auto alloc = [&](size_t bytes) -> void* {
    off = (off + 255) & ~(size_t)255;
    void* p = ws + off;
    off += bytes;
    return p;
  };
  _Float16* xtan = (_Float16*)alloc((size_t)N * 128 * 2);  // reused as agg (f16)
  _Float16* qkv  = (_Float16*)alloc((size_t)N * 384 * 2);
  float* outlin  = (float*)alloc((size_t)N * 128 * 4);
  int* rperm     = (int*)alloc((size_t)E * 4);
  _Float16* Wc   = (_Float16*)alloc(384 * 128 * 2);
  _Float16* Wof  = (_Float16*)alloc(128 * 128 * 2);
  int* cnt       = (int*)alloc((size_t)(N + 1) * 4);
  int* offs      = (int*)alloc((size_t)(N + 1) * 4);
  int* cur       = (int*)alloc((size_t)N * 4);

  hipMemsetAsync(cnt, 0, (size_t)(N + 1) * 4, stream);
  build_wcomb<<<192, 256, 0, stream>>>(Wq, Wk, Wv, Wc);
  build_wo16<<<64, 256, 0, stream>>>(Wo, Wof);
  xtan_kernel<<<N, 128, 0, stream>>>(x, xtan, N);
  gemm_mfma<3, true><<<(N + 63) / 64, 256, 0, stream>>>(xtan, Wc, qkv, nullptr, N);
  count_kernel<<<(E + 255) / 256, 256, 0, stream>>>(col, cnt, E);
  scan_kernel<<<1, 1024, 0, stream>>>(cnt, offs, cur, N);
  scatter_kernel<<<(E + 255) / 256, 256, 0, stream>>>(col, row, cur, rperm, E);
  attn_kernel<<<(N + 3) / 4, 256, 0, stream>>>((const half2v*)qkv, rperm, offs, (half2v*)xtan, N);
  gemm_mfma<1, false><<<(N + 63) / 64, 256, 0, stream>>>(xtan, Wof, outlin, bo, N);
  expmap_kernel<<<N, 128, 0, stream>>>(outlin, out, N);
}

// Round 4
// 316.675 us; speedup vs baseline: 1.7920x; 1.1242x over previous
//
#include <hip/hip_runtime.h>
#include <math.h>

#define EPS 1e-7f
#define SCALE 0.17677669529663687f  // 32^-0.5

typedef _Float16 half2v __attribute__((ext_vector_type(2)));
typedef _Float16 f16x4 __attribute__((ext_vector_type(4)));
typedef _Float16 f16x8 __attribute__((ext_vector_type(8)));
typedef float f32x4 __attribute__((ext_vector_type(4)));

__device__ __forceinline__ void gload16(const void* g, void* l) {
  __builtin_amdgcn_global_load_lds(
      (const __attribute__((address_space(1))) unsigned int*)g,
      (__attribute__((address_space(3))) unsigned int*)l, 16, 0, 0);
}

// ---------- weight convert: Wcomb (384x128 f16) = [Wq;Wk;Wv] rows=out col ----
__global__ __launch_bounds__(256) void build_wcomb(
    const float* __restrict__ Wq, const float* __restrict__ Wk,
    const float* __restrict__ Wv, _Float16* __restrict__ Wc) {
  int o = blockIdx.x * 256 + threadIdx.x;
  if (o >= 384 * 128) return;
  int j = o >> 7;
  int i = o & 127;
  const float* W = (j < 128) ? Wq : (j < 256) ? Wk : Wv;
  Wc[o] = (_Float16)W[(j & 127) * 128 + i];
}

__global__ __launch_bounds__(256) void build_wo16(
    const float* __restrict__ Wo, _Float16* __restrict__ Wof) {
  int o = blockIdx.x * 256 + threadIdx.x;
  if (o >= 128 * 128) return;
  Wof[o] = (_Float16)Wo[o];
}

// ---------- log map at origin: x (N x 129) -> x_tan (N x 128) f16 ----------
__global__ __launch_bounds__(128) void xtan_kernel(
    const float* __restrict__ x, _Float16* __restrict__ xt, int N) {
  int n = blockIdx.x;
  int t = threadIdx.x;
  float xs = x[n * 129 + 1 + t];
  float ss = xs * xs;
#pragma unroll
  for (int o = 32; o >= 1; o >>= 1) ss += __shfl_xor(ss, o, 64);
  __shared__ float wred[2];
  if ((t & 63) == 0) wred[t >> 6] = ss;
  __syncthreads();
  float tot = wred[0] + wred[1];
  float norm = sqrtf(tot + EPS);
  float x0 = x[n * 129];
  float dist = acoshf(fmaxf(x0, 1.0f + EPS));
  xt[n * 128 + t] = (_Float16)((dist / norm) * xs);
}

// ---------- f16 MFMA GEMM ----------
// MODE 0 (NCHUNKS=3): C0 = Q (f16 Mx128), C1 = KV interleaved f16 Mx256:
//                     [m][hd] = {K[2hd],K[2hd+1],V[2hd],V[2hd+1]}
// MODE 1 (NCHUNKS=1): C0 = f32 Mx128 with +bias
template <int NCHUNKS, int MODE>
__global__ __launch_bounds__(256, 3) void gemm_mfma(
    const _Float16* __restrict__ A,   // M x 128
    const _Float16* __restrict__ B,   // (NCHUNKS*128) x 128, rows = out cols
    void* __restrict__ C0, void* __restrict__ C1,
    const float* __restrict__ bias, int M) {
  __shared__ _Float16 As[64 * 128];
  __shared__ _Float16 Bs[128 * 128];
  const int tid = threadIdx.x;
  const int wave = tid >> 6;
  const int lane = tid & 63;
  const int wm = wave >> 1, wn = wave & 1;
  const int lrow = lane & 15, q = lane >> 4;
  const int m0 = blockIdx.x * 64;

  // stage A once: 1024 16B chunks; slot p holds logical (m=p>>4, kc=(p&15)^(m&15))
#pragma unroll
  for (int j = 0; j < 4; j++) {
    int slot0 = (j * 4 + wave) * 64;
    int p = slot0 + lane;
    int m = p >> 4;
    int kcl = (p & 15) ^ (m & 15);
    int msrc = m0 + m;
    if (msrc > M - 1) msrc = M - 1;
    gload16(A + (size_t)msrc * 128 + kcl * 8, (char*)As + (size_t)slot0 * 16);
  }

  for (int c = 0; c < NCHUNKS; c++) {
#pragma unroll
    for (int j = 0; j < 8; j++) {
      int slot0 = (j * 4 + wave) * 64;
      int p = slot0 + lane;
      int n = p >> 4;
      int kcl = (p & 15) ^ (n & 15);
      gload16(B + ((size_t)(c * 128 + n)) * 128 + kcl * 8, (char*)Bs + (size_t)slot0 * 16);
    }
    __syncthreads();

    f32x4 acc[2][4];
#pragma unroll
    for (int mt = 0; mt < 2; mt++)
#pragma unroll
      for (int nt = 0; nt < 4; nt++) acc[mt][nt] = (f32x4)0.f;

    const f16x8* Av = (const f16x8*)As;
    const f16x8* Bv = (const f16x8*)Bs;
#pragma unroll
    for (int s = 0; s < 4; s++) {
      int kc = s * 4 + q;
      f16x8 af[2], bf[4];
#pragma unroll
      for (int mt = 0; mt < 2; mt++) {
        int m = wm * 32 + mt * 16 + lrow;
        af[mt] = Av[m * 16 + (kc ^ (m & 15))];
      }
#pragma unroll
      for (int nt = 0; nt < 4; nt++) {
        int n = wn * 64 + nt * 16 + lrow;
        bf[nt] = Bv[n * 16 + (kc ^ (n & 15))];
      }
#pragma unroll
      for (int mt = 0; mt < 2; mt++)
#pragma unroll
        for (int nt = 0; nt < 4; nt++)
          acc[mt][nt] = __builtin_amdgcn_mfma_f32_16x16x32_f16(af[mt], bf[nt], acc[mt][nt], 0, 0, 0);
    }

    // epilogue: D lane layout col=lane&15, row=q*4+reg
#pragma unroll
    for (int mt = 0; mt < 2; mt++) {
#pragma unroll
      for (int reg = 0; reg < 4; reg++) {
        int rg = m0 + wm * 32 + mt * 16 + q * 4 + reg;
        if (rg < M) {
#pragma unroll
          for (int nt = 0; nt < 4; nt++) {
            int cl = wn * 64 + nt * 16 + lrow;
            float v = acc[mt][nt][reg];
            if (MODE == 1) {
              ((float*)C0)[(size_t)rg * 128 + cl] = v + bias[cl];
            } else {
              _Float16 hv = (_Float16)v;
              if (c == 0) {
                ((_Float16*)C0)[(size_t)rg * 128 + cl] = hv;
              } else {
                // KV interleave: {k0,k1,v0,v1} per hd=cl>>1
                ((_Float16*)C1)[(size_t)rg * 256 + (cl >> 1) * 4 + (cl & 1) + ((c == 2) ? 2 : 0)] = hv;
              }
            }
          }
        }
      }
    }
    if (c + 1 < NCHUNKS) __syncthreads();
  }
}

// ---------- CSR build ----------
__global__ __launch_bounds__(256) void count_kernel(
    const int* __restrict__ col, int* __restrict__ cnt, int E) {
  int e = blockIdx.x * 256 + threadIdx.x;
  if (e < E) atomicAdd(&cnt[col[e]], 1);
}

// 3-pass parallel scan: tiles of 1024 (256 thr x 4 elems)
__global__ __launch_bounds__(256) void scan_part(
    const int* __restrict__ cnt, int* __restrict__ bsum, int N) {
  int base = blockIdx.x * 1024;
  int t = threadIdx.x;
  int i = base + t * 4;
  int4 v = make_int4(0, 0, 0, 0);
  if (i + 3 < N) v = *reinterpret_cast<const int4*>(&cnt[i]);
  else {
    if (i < N) v.x = cnt[i];
    if (i + 1 < N) v.y = cnt[i + 1];
    if (i + 2 < N) v.z = cnt[i + 2];
    if (i + 3 < N) v.w = cnt[i + 3];
  }
  int s = v.x + v.y + v.z + v.w;
#pragma unroll
  for (int o = 32; o >= 1; o >>= 1) s += __shfl_xor(s, o, 64);
  __shared__ int ws[4];
  if ((t & 63) == 0) ws[t >> 6] = s;
  __syncthreads();
  if (t == 0) bsum[blockIdx.x] = ws[0] + ws[1] + ws[2] + ws[3];
}

__global__ __launch_bounds__(64) void scan_tops(
    const int* __restrict__ bsum, int* __restrict__ bbase,
    int* __restrict__ offsN, int nb) {
  int t = threadIdx.x;  // nb <= 64
  int v = (t < nb) ? bsum[t] : 0;
  int inc = v;
#pragma unroll
  for (int d = 1; d < 64; d <<= 1) {
    int u = __shfl_up(inc, d, 64);
    if (t >= d) inc += u;
  }
  if (t < nb) bbase[t] = inc - v;
  if (t == 63) *offsN = inc;
}

__global__ __launch_bounds__(256) void scan_final(
    const int* __restrict__ cnt, const int* __restrict__ bbase,
    int* __restrict__ offs, int* __restrict__ cur, int N) {
  int base = blockIdx.x * 1024;
  int t = threadIdx.x;
  int lane = t & 63, w = t >> 6;
  int i = base + t * 4;
  int4 v = make_int4(0, 0, 0, 0);
  if (i + 3 < N) v = *reinterpret_cast<const int4*>(&cnt[i]);
  else {
    if (i < N) v.x = cnt[i];
    if (i + 1 < N) v.y = cnt[i + 1];
    if (i + 2 < N) v.z = cnt[i + 2];
    if (i + 3 < N) v.w = cnt[i + 3];
  }
  int s = v.x + v.y + v.z + v.w;
  int inc = s;
#pragma unroll
  for (int d = 1; d < 64; d <<= 1) {
    int u = __shfl_up(inc, d, 64);
    if (lane >= d) inc += u;
  }
  __shared__ int ws[4];
  if (lane == 63) ws[w] = inc;
  __syncthreads();
  int wb = 0;
  for (int k = 0; k < 4; k++) wb += (k < w) ? ws[k] : 0;
  int excl = bbase[blockIdx.x] + wb + inc - s;
  int o0 = excl, o1 = o0 + v.x, o2 = o1 + v.y, o3 = o2 + v.z;
  if (i < N) { offs[i] = o0; cur[i] = o0; }
  if (i + 1 < N) { offs[i + 1] = o1; cur[i + 1] = o1; }
  if (i + 2 < N) { offs[i + 2] = o2; cur[i + 2] = o2; }
  if (i + 3 < N) { offs[i + 3] = o3; cur[i + 3] = o3; }
}

__global__ __launch_bounds__(256) void scatter_kernel(
    const int* __restrict__ col, const int* __restrict__ row,
    int* __restrict__ cur, int* __restrict__ rperm, int E) {
  int e = blockIdx.x * 256 + threadIdx.x;
  if (e < E) {
    int pos = atomicAdd(&cur[col[e]], 1);
    rperm[pos] = row[e];
  }
}

// ---------- node-centric graph attention, no-max softmax (scores bounded) ----
// 1 wave per node; lane hd = h*16+di owns dims {2di,2di+1} of head h.
// KVI[node][hd] = {kx,ky,vx,vy} f16 -> ONE 8B gather per edge per lane.
__global__ __launch_bounds__(256) void attn_kernel(
    const half2v* __restrict__ Qb,   // N x 64 half2
    const f16x4* __restrict__ KVI,   // N x 64 f16x4
    const int* __restrict__ rperm, const int* __restrict__ offs,
    half2v* __restrict__ agg, int N) {
  int node = blockIdx.x * 4 + (threadIdx.x >> 6);
  if (node >= N) return;
  int hd = threadIdx.x & 63;
  half2v qh = Qb[(size_t)node * 64 + hd];
  float qx = (float)qh.x, qy = (float)qh.y;
  int s0 = offs[node], s1 = offs[node + 1];
  float l = 0.f, ax = 0.f, ay = 0.f;
  int i = s0;
  for (; i + 4 <= s1; i += 4) {
    int r0 = rperm[i], r1 = rperm[i + 1], r2 = rperm[i + 2], r3 = rperm[i + 3];
    f16x4 a0 = KVI[(size_t)r0 * 64 + hd];
    f16x4 a1 = KVI[(size_t)r1 * 64 + hd];
    f16x4 a2 = KVI[(size_t)r2 * 64 + hd];
    f16x4 a3 = KVI[(size_t)r3 * 64 + hd];
    float p0 = fmaf(qx, (float)a0[0], qy * (float)a0[1]);
    float p1 = fmaf(qx, (float)a1[0], qy * (float)a1[1]);
    float p2 = fmaf(qx, (float)a2[0], qy * (float)a2[1]);
    float p3 = fmaf(qx, (float)a3[0], qy * (float)a3[1]);
#pragma unroll
    for (int o = 8; o >= 1; o >>= 1) {
      p0 += __shfl_xor(p0, o, 16);
      p1 += __shfl_xor(p1, o, 16);
      p2 += __shfl_xor(p2, o, 16);
      p3 += __shfl_xor(p3, o, 16);
    }
    float e0 = __expf(p0 * SCALE), e1 = __expf(p1 * SCALE);
    float e2 = __expf(p2 * SCALE), e3 = __expf(p3 * SCALE);
    l += (e0 + e1) + (e2 + e3);
    ax = fmaf(e0, (float)a0[2], ax); ay = fmaf(e0, (float)a0[3], ay);
    ax = fmaf(e1, (float)a1[2], ax); ay = fmaf(e1, (float)a1[3], ay);
    ax = fmaf(e2, (float)a2[2], ax); ay = fmaf(e2, (float)a2[3], ay);
    ax = fmaf(e3, (float)a3[2], ax); ay = fmaf(e3, (float)a3[3], ay);
  }
  for (; i < s1; i++) {
    int r0 = rperm[i];
    f16x4 a0 = KVI[(size_t)r0 * 64 + hd];
    float p0 = fmaf(qx, (float)a0[0], qy * (float)a0[1]);
#pragma unroll
    for (int o = 8; o >= 1; o >>= 1) p0 += __shfl_xor(p0, o, 16);
    float e0 = __expf(p0 * SCALE);
    l += e0;
    ax = fmaf(e0, (float)a0[2], ax); ay = fmaf(e0, (float)a0[3], ay);
  }
  float inv = (l > 0.f) ? 1.0f / l : 0.f;
  half2v o2;
  o2.x = (_Float16)(ax * inv);
  o2.y = (_Float16)(ay * inv);
  agg[(size_t)node * 64 + hd] = o2;
}

// ---------- exp map at origin: vlin (N x 128) -> out (N x 129) ----------
__global__ __launch_bounds__(128) void expmap_kernel(
    const float* __restrict__ vlin, float* __restrict__ out, int N) {
  int n = blockIdx.x;
  int t = threadIdx.x;
  float v = vlin[(size_t)n * 128 + t];
  float ss = v * v;
#pragma unroll
  for (int o = 32; o >= 1; o >>= 1) ss += __shfl_xor(ss, o, 64);
  __shared__ float wred[2];
  if ((t & 63) == 0) wred[t >> 6] = ss;
  __syncthreads();
  float tot = wred[0] + wred[1];
  float r = sqrtf(tot + EPS);
  float s = sinhf(r) / r;
  out[(size_t)n * 129 + 1 + t] = s * v;
  if (t == 0) out[(size_t)n * 129] = coshf(r);
}

extern "C" void kernel_launch(void* const* d_in, const int* in_sizes, int n_in,
                              void* d_out, int out_size, void* d_ws, size_t ws_size,
                              hipStream_t stream) {
  const float* x = (const float*)d_in[0];
  const int* ei = (const int*)d_in[1];
  const float* Wq = (const float*)d_in[2];
  const float* Wk = (const float*)d_in[3];
  const float* Wv = (const float*)d_in[4];
  const float* Wo = (const float*)d_in[5];
  const float* bo = (const float*)d_in[6];
  float* out = (float*)d_out;

  const int N = in_sizes[0] / 129;
  const int E = in_sizes[1] / 2;
  const int* row = ei;       // edge_index[0]
  const int* col = ei + E;   // edge_index[1]

  char* ws = (char*)d_ws;
  size_t off = 0;
  auto alloc = [&](size_t bytes) -> void* {
    off = (off + 255) & ~(size_t)255;
    void* p = ws + off;
    off += bytes;
    return p;
  };
  _Float16* xtan = (_Float16*)alloc((size_t)N * 128 * 2);  // reused as agg (f16)
  _Float16* qbuf = (_Float16*)alloc((size_t)N * 128 * 2);
  _Float16* kvi  = (_Float16*)alloc((size_t)N * 256 * 2);
  float* outlin  = (float*)alloc((size_t)N * 128 * 4);
  int* rperm     = (int*)alloc((size_t)E * 4);
  _Float16* Wc   = (_Float16*)alloc(384 * 128 * 2);
  _Float16* Wof  = (_Float16*)alloc(128 * 128 * 2);
  int* cnt       = (int*)alloc((size_t)(N + 1) * 4);
  int* offs      = (int*)alloc((size_t)(N + 1) * 4);
  int* cur       = (int*)alloc((size_t)N * 4);
  int* bsum      = (int*)alloc(64 * 4);
  int* bbase     = (int*)alloc(64 * 4);

  const int nb = (N + 1023) / 1024;  // 49 for N=50000 (<=64 supported)

  hipMemsetAsync(cnt, 0, (size_t)(N + 1) * 4, stream);
  build_wcomb<<<192, 256, 0, stream>>>(Wq, Wk, Wv, Wc);
  build_wo16<<<64, 256, 0, stream>>>(Wo, Wof);
  xtan_kernel<<<N, 128, 0, stream>>>(x, xtan, N);
  gemm_mfma<3, 0><<<(N + 63) / 64, 256, 0, stream>>>(xtan, Wc, qbuf, kvi, nullptr, N);
  count_kernel<<<(E + 255) / 256, 256, 0, stream>>>(col, cnt, E);
  scan_part<<<nb, 256, 0, stream>>>(cnt, bsum, N);
  scan_tops<<<1, 64, 0, stream>>>(bsum, bbase, &offs[N], nb);
  scan_final<<<nb, 256, 0, stream>>>(cnt, bbase, offs, cur, N);
  scatter_kernel<<<(E + 255) / 256, 256, 0, stream>>>(col, row, cur, rperm, E);
  attn_kernel<<<(N + 3) / 4, 256, 0, stream>>>((const half2v*)qbuf, (const f16x4*)kvi,
                                               rperm, offs, (half2v*)xtan, N);
  gemm_mfma<1, 1><<<(N + 63) / 64, 256, 0, stream>>>(xtan, Wof, outlin, nullptr, bo, N);
  expmap_kernel<<<N, 128, 0, stream>>>(outlin, out, N);
}

// Round 5
// 280.699 us; speedup vs baseline: 2.0216x; 1.1282x over previous
//
#include <hip/hip_runtime.h>
#include <math.h>

#define EPS 1e-7f
#define SCALE 0.17677669529663687f  // 32^-0.5

typedef _Float16 half2v __attribute__((ext_vector_type(2)));
typedef _Float16 f16x4 __attribute__((ext_vector_type(4)));
typedef _Float16 f16x8 __attribute__((ext_vector_type(8)));
typedef float f32x4 __attribute__((ext_vector_type(4)));

__device__ __forceinline__ void gload16(const void* g, void* l) {
  __builtin_amdgcn_global_load_lds(
      (const __attribute__((address_space(1))) unsigned int*)g,
      (__attribute__((address_space(3))) unsigned int*)l, 16, 0, 0);
}

// ---------- weight convert (fused): Wc (384x128 f16) + Wof (128x128 f16) ----
__global__ __launch_bounds__(256) void build_weights(
    const float* __restrict__ Wq, const float* __restrict__ Wk,
    const float* __restrict__ Wv, const float* __restrict__ Wo,
    _Float16* __restrict__ Wc, _Float16* __restrict__ Wof) {
  int o = blockIdx.x * 256 + threadIdx.x;
  if (o >= 512 * 128) return;
  int j = o >> 7;
  int i = o & 127;
  if (j < 384) {
    const float* W = (j < 128) ? Wq : (j < 256) ? Wk : Wv;
    Wc[o] = (_Float16)W[(j & 127) * 128 + i];
  } else {
    Wof[(j - 384) * 128 + i] = (_Float16)Wo[(j - 384) * 128 + i];
  }
}

// ---------- log map (wave-per-node) + cnt zeroing ----------
__global__ __launch_bounds__(256) void xtan_kernel(
    const float* __restrict__ x, _Float16* __restrict__ xt,
    int* __restrict__ cnt, int N) {
  int node = blockIdx.x * 4 + (threadIdx.x >> 6);
  if (node >= N) return;
  int lane = threadIdx.x & 63;
  float2 xs = *reinterpret_cast<const float2*>(&x[(size_t)node * 129 + 1 + lane * 2]);
  float ss = fmaf(xs.x, xs.x, xs.y * xs.y);
#pragma unroll
  for (int o = 32; o >= 1; o >>= 1) ss += __shfl_xor(ss, o, 64);
  float norm = sqrtf(ss + EPS);
  float x0 = x[(size_t)node * 129];
  float dist = acoshf(fmaxf(x0, 1.0f + EPS));
  float sc = dist / norm;
  half2v h;
  h.x = (_Float16)(sc * xs.x);
  h.y = (_Float16)(sc * xs.y);
  *reinterpret_cast<half2v*>(&xt[(size_t)node * 128 + lane * 2]) = h;
  if (lane == 0) cnt[node] = 0;
}

// ---------- f16 MFMA GEMM ----------
// MODE 0 (NCHUNKS=3): C0 = Q (f16 Mx128); C1 = KVI: per node 32 chunks of
//   16B: chunk(h,d4) = {K[h*32+4d4..+3], V[h*32+4d4..+3]} (f16 each)
// MODE 1 (NCHUNKS=1): fused out-proj + bias + exp-map -> C0 = out (M x 129 f32)
template <int NCHUNKS, int MODE>
__global__ __launch_bounds__(256, 3) void gemm_mfma(
    const _Float16* __restrict__ A,   // M x 128
    const _Float16* __restrict__ B,   // (NCHUNKS*128) x 128, rows = out cols
    void* __restrict__ C0, void* __restrict__ C1,
    const float* __restrict__ bias, int M) {
  __shared__ _Float16 As[64 * 128];
  __shared__ _Float16 Bs[128 * 128];
  const int tid = threadIdx.x;
  const int wave = tid >> 6;
  const int lane = tid & 63;
  const int wm = wave >> 1, wn = wave & 1;
  const int lrow = lane & 15, q = lane >> 4;
  const int m0 = blockIdx.x * 64;

  // stage A once: 1024 16B chunks; slot p holds logical (m=p>>4, kc=(p&15)^(m&15))
#pragma unroll
  for (int j = 0; j < 4; j++) {
    int slot0 = (j * 4 + wave) * 64;
    int p = slot0 + lane;
    int m = p >> 4;
    int kcl = (p & 15) ^ (m & 15);
    int msrc = m0 + m;
    if (msrc > M - 1) msrc = M - 1;
    gload16(A + (size_t)msrc * 128 + kcl * 8, (char*)As + (size_t)slot0 * 16);
  }

  f32x4 acc[2][4];
  for (int c = 0; c < NCHUNKS; c++) {
#pragma unroll
    for (int j = 0; j < 8; j++) {
      int slot0 = (j * 4 + wave) * 64;
      int p = slot0 + lane;
      int n = p >> 4;
      int kcl = (p & 15) ^ (n & 15);
      gload16(B + ((size_t)(c * 128 + n)) * 128 + kcl * 8, (char*)Bs + (size_t)slot0 * 16);
    }
    __syncthreads();

#pragma unroll
    for (int mt = 0; mt < 2; mt++)
#pragma unroll
      for (int nt = 0; nt < 4; nt++) acc[mt][nt] = (f32x4)0.f;

    const f16x8* Av = (const f16x8*)As;
    const f16x8* Bv = (const f16x8*)Bs;
#pragma unroll
    for (int s = 0; s < 4; s++) {
      int kc = s * 4 + q;
      f16x8 af[2], bf[4];
#pragma unroll
      for (int mt = 0; mt < 2; mt++) {
        int m = wm * 32 + mt * 16 + lrow;
        af[mt] = Av[m * 16 + (kc ^ (m & 15))];
      }
#pragma unroll
      for (int nt = 0; nt < 4; nt++) {
        int n = wn * 64 + nt * 16 + lrow;
        bf[nt] = Bv[n * 16 + (kc ^ (n & 15))];
      }
#pragma unroll
      for (int mt = 0; mt < 2; mt++)
#pragma unroll
        for (int nt = 0; nt < 4; nt++)
          acc[mt][nt] = __builtin_amdgcn_mfma_f32_16x16x32_f16(af[mt], bf[nt], acc[mt][nt], 0, 0, 0);
    }

    if (MODE == 0) {
      // D lane layout: col=lane&15 (lrow), row=q*4+reg
#pragma unroll
      for (int mt = 0; mt < 2; mt++) {
#pragma unroll
        for (int reg = 0; reg < 4; reg++) {
          int rg = m0 + wm * 32 + mt * 16 + q * 4 + reg;
          if (rg < M) {
#pragma unroll
            for (int nt = 0; nt < 4; nt++) {
              int cl = wn * 64 + nt * 16 + lrow;
              _Float16 hv = (_Float16)acc[mt][nt][reg];
              if (c == 0) {
                ((_Float16*)C0)[(size_t)rg * 128 + cl] = hv;
              } else {
                int h = cl >> 5, j = cl & 31;
                int idx = (h * 8 + (j >> 2)) * 8 + ((c == 2) ? 4 : 0) + (j & 3);
                ((_Float16*)C1)[(size_t)rg * 256 + idx] = hv;
              }
            }
          }
        }
      }
      if (c + 1 < NCHUNKS) __syncthreads();
    }
  }

  if (MODE == 1) {
    // fused bias + exp-map epilogue
    float* out = (float*)C0;
    __syncthreads();               // all waves done reading LDS
    float* rsum = (float*)As;      // 64 rows x 2 (wn)
#pragma unroll
    for (int mt = 0; mt < 2; mt++)
#pragma unroll
      for (int nt = 0; nt < 4; nt++) {
        int cl = wn * 64 + nt * 16 + lrow;
        float b = bias[cl];
#pragma unroll
        for (int reg = 0; reg < 4; reg++) acc[mt][nt][reg] += b;
      }
#pragma unroll
    for (int mt = 0; mt < 2; mt++) {
#pragma unroll
      for (int reg = 0; reg < 4; reg++) {
        float s4 = 0.f;
#pragma unroll
        for (int nt = 0; nt < 4; nt++) s4 = fmaf(acc[mt][nt][reg], acc[mt][nt][reg], s4);
#pragma unroll
        for (int o = 8; o >= 1; o >>= 1) s4 += __shfl_xor(s4, o, 16);
        if (lrow == 0) rsum[(wm * 32 + mt * 16 + q * 4 + reg) * 2 + wn] = s4;
      }
    }
    __syncthreads();
#pragma unroll
    for (int mt = 0; mt < 2; mt++) {
#pragma unroll
      for (int reg = 0; reg < 4; reg++) {
        int rl = wm * 32 + mt * 16 + q * 4 + reg;
        int rg = m0 + rl;
        if (rg < M) {
          float tot = rsum[rl * 2] + rsum[rl * 2 + 1];
          float r = sqrtf(tot + EPS);
          float s = sinhf(r) / r;
#pragma unroll
          for (int nt = 0; nt < 4; nt++) {
            int cl = wn * 64 + nt * 16 + lrow;
            out[(size_t)rg * 129 + 1 + cl] = s * acc[mt][nt][reg];
          }
          if (wn == 0 && lrow == 0) out[(size_t)rg * 129] = coshf(r);
        }
      }
    }
  }
}

// ---------- CSR build ----------
__global__ __launch_bounds__(256) void count_kernel(
    const int* __restrict__ col, int* __restrict__ cnt, int E) {
  int e = blockIdx.x * 256 + threadIdx.x;
  if (e < E) atomicAdd(&cnt[col[e]], 1);
}

// pass 1: per-1024-tile sums
__global__ __launch_bounds__(256) void scan_part(
    const int* __restrict__ cnt, int* __restrict__ bsum, int N) {
  int base = blockIdx.x * 1024;
  int t = threadIdx.x;
  int i = base + t * 4;
  int4 v = make_int4(0, 0, 0, 0);
  if (i + 3 < N) v = *reinterpret_cast<const int4*>(&cnt[i]);
  else {
    if (i < N) v.x = cnt[i];
    if (i + 1 < N) v.y = cnt[i + 1];
    if (i + 2 < N) v.z = cnt[i + 2];
    if (i + 3 < N) v.w = cnt[i + 3];
  }
  int s = v.x + v.y + v.z + v.w;
#pragma unroll
  for (int o = 32; o >= 1; o >>= 1) s += __shfl_xor(s, o, 64);
  __shared__ int ws[4];
  if ((t & 63) == 0) ws[t >> 6] = s;
  __syncthreads();
  if (t == 0) bsum[blockIdx.x] = ws[0] + ws[1] + ws[2] + ws[3];
}

// pass 2: each block redundantly scans bsum (nb<=64), then finalizes its tile
__global__ __launch_bounds__(256) void scan_final(
    const int* __restrict__ cnt, const int* __restrict__ bsum,
    int* __restrict__ offs, int* __restrict__ cur, int N, int nb) {
  __shared__ int base_sh;
  __shared__ int ws[4];
  int t = threadIdx.x;
  if (t < 64) {
    int v = (t < nb) ? bsum[t] : 0;
    int inc = v;
#pragma unroll
    for (int d = 1; d < 64; d <<= 1) {
      int u = __shfl_up(inc, d, 64);
      if (t >= d) inc += u;
    }
    if (t == (int)blockIdx.x) base_sh = inc - v;
    if (blockIdx.x == 0 && t == 63) offs[N] = inc;
  }
  __syncthreads();
  int base = blockIdx.x * 1024;
  int lane = t & 63, w = t >> 6;
  int i = base + t * 4;
  int4 v = make_int4(0, 0, 0, 0);
  if (i + 3 < N) v = *reinterpret_cast<const int4*>(&cnt[i]);
  else {
    if (i < N) v.x = cnt[i];
    if (i + 1 < N) v.y = cnt[i + 1];
    if (i + 2 < N) v.z = cnt[i + 2];
    if (i + 3 < N) v.w = cnt[i + 3];
  }
  int s = v.x + v.y + v.z + v.w;
  int inc = s;
#pragma unroll
  for (int d = 1; d < 64; d <<= 1) {
    int u = __shfl_up(inc, d, 64);
    if (lane >= d) inc += u;
  }
  if (lane == 63) ws[w] = inc;
  __syncthreads();
  int wb = 0;
  for (int k = 0; k < 4; k++) wb += (k < w) ? ws[k] : 0;
  int excl = base_sh + wb + inc - s;
  int o0 = excl, o1 = o0 + v.x, o2 = o1 + v.y, o3 = o2 + v.z;
  if (i < N) { offs[i] = o0; cur[i] = o0; }
  if (i + 1 < N) { offs[i + 1] = o1; cur[i + 1] = o1; }
  if (i + 2 < N) { offs[i + 2] = o2; cur[i + 2] = o2; }
  if (i + 3 < N) { offs[i + 3] = o3; cur[i + 3] = o3; }
}

__global__ __launch_bounds__(256) void scatter_kernel(
    const int* __restrict__ col, const int* __restrict__ row,
    int* __restrict__ cur, int* __restrict__ rperm, int E) {
  int e = blockIdx.x * 256 + threadIdx.x;
  if (e < E) {
    int pos = atomicAdd(&cur[col[e]], 1);
    rperm[pos] = row[e];
  }
}

// ---------- node-centric attention: 1 wave/node, 2 edges in flight ----------
// lane = par*32 + h*8 + d4; lane owns dims h*32+4*d4..+3; par half = own edge.
__global__ __launch_bounds__(256) void attn_kernel(
    const _Float16* __restrict__ Qb,  // N x 128 f16
    const f16x8* __restrict__ KVI,    // N x 32 chunks {K4,V4}
    const int* __restrict__ rperm, const int* __restrict__ offs,
    _Float16* __restrict__ agg, int N) {
  int node = blockIdx.x * 4 + (threadIdx.x >> 6);
  if (node >= N) return;
  int lane = threadIdx.x & 63;
  int par = lane >> 5;
  int hd = lane & 31;  // h*8+d4
  int qoff = hd * 4;   // = h*32 + d4*4
  f16x4 qh = *reinterpret_cast<const f16x4*>(Qb + (size_t)node * 128 + qoff);
  float q0 = (float)qh[0], q1 = (float)qh[1], q2 = (float)qh[2], q3 = (float)qh[3];
  int s0 = offs[node], s1 = offs[node + 1];
  float l = 0.f, av0 = 0.f, av1 = 0.f, av2 = 0.f, av3 = 0.f;
  int i = s0;
  for (; i + 4 <= s1; i += 4) {
    int rA = rperm[i + par];
    int rB = rperm[i + 2 + par];
    f16x8 a = KVI[(size_t)rA * 32 + hd];
    f16x8 b = KVI[(size_t)rB * 32 + hd];
    float pA = fmaf(q0, (float)a[0], fmaf(q1, (float)a[1], fmaf(q2, (float)a[2], q3 * (float)a[3])));
    float pB = fmaf(q0, (float)b[0], fmaf(q1, (float)b[1], fmaf(q2, (float)b[2], q3 * (float)b[3])));
#pragma unroll
    for (int o = 4; o >= 1; o >>= 1) {
      pA += __shfl_xor(pA, o, 8);
      pB += __shfl_xor(pB, o, 8);
    }
    float eA = __expf(pA * SCALE);
    float eB = __expf(pB * SCALE);
    l += eA + eB;
    av0 = fmaf(eA, (float)a[4], av0); av0 = fmaf(eB, (float)b[4], av0);
    av1 = fmaf(eA, (float)a[5], av1); av1 = fmaf(eB, (float)b[5], av1);
    av2 = fmaf(eA, (float)a[6], av2); av2 = fmaf(eB, (float)b[6], av2);
    av3 = fmaf(eA, (float)a[7], av3); av3 = fmaf(eB, (float)b[7], av3);
  }
  if (i + 2 <= s1) {
    int rA = rperm[i + par];
    f16x8 a = KVI[(size_t)rA * 32 + hd];
    float pA = fmaf(q0, (float)a[0], fmaf(q1, (float)a[1], fmaf(q2, (float)a[2], q3 * (float)a[3])));
#pragma unroll
    for (int o = 4; o >= 1; o >>= 1) pA += __shfl_xor(pA, o, 8);
    float eA = __expf(pA * SCALE);
    l += eA;
    av0 = fmaf(eA, (float)a[4], av0);
    av1 = fmaf(eA, (float)a[5], av1);
    av2 = fmaf(eA, (float)a[6], av2);
    av3 = fmaf(eA, (float)a[7], av3);
    i += 2;
  }
  if (i < s1) {  // last lone edge: only par==0 half accumulates
    int r = rperm[i];
    f16x8 a = KVI[(size_t)r * 32 + hd];
    float p = fmaf(q0, (float)a[0], fmaf(q1, (float)a[1], fmaf(q2, (float)a[2], q3 * (float)a[3])));
#pragma unroll
    for (int o = 4; o >= 1; o >>= 1) p += __shfl_xor(p, o, 8);
    float e = __expf(p * SCALE) * (par ? 0.f : 1.f);
    l += e;
    av0 = fmaf(e, (float)a[4], av0);
    av1 = fmaf(e, (float)a[5], av1);
    av2 = fmaf(e, (float)a[6], av2);
    av3 = fmaf(e, (float)a[7], av3);
  }
  // merge the two edge-parity halves
  l += __shfl_xor(l, 32, 64);
  av0 += __shfl_xor(av0, 32, 64);
  av1 += __shfl_xor(av1, 32, 64);
  av2 += __shfl_xor(av2, 32, 64);
  av3 += __shfl_xor(av3, 32, 64);
  if (par == 0) {
    float inv = (l > 0.f) ? 1.0f / l : 0.f;
    f16x4 o4;
    o4[0] = (_Float16)(av0 * inv);
    o4[1] = (_Float16)(av1 * inv);
    o4[2] = (_Float16)(av2 * inv);
    o4[3] = (_Float16)(av3 * inv);
    *reinterpret_cast<f16x4*>(agg + (size_t)node * 128 + qoff) = o4;
  }
}

extern "C" void kernel_launch(void* const* d_in, const int* in_sizes, int n_in,
                              void* d_out, int out_size, void* d_ws, size_t ws_size,
                              hipStream_t stream) {
  const float* x = (const float*)d_in[0];
  const int* ei = (const int*)d_in[1];
  const float* Wq = (const float*)d_in[2];
  const float* Wk = (const float*)d_in[3];
  const float* Wv = (const float*)d_in[4];
  const float* Wo = (const float*)d_in[5];
  const float* bo = (const float*)d_in[6];
  float* out = (float*)d_out;

  const int N = in_sizes[0] / 129;
  const int E = in_sizes[1] / 2;
  const int* row = ei;       // edge_index[0]
  const int* col = ei + E;   // edge_index[1]

  char* ws = (char*)d_ws;
  size_t off = 0;
  auto alloc = [&](size_t bytes) -> void* {
    off = (off + 255) & ~(size_t)255;
    void* p = ws + off;
    off += bytes;
    return p;
  };
  _Float16* xtan = (_Float16*)alloc((size_t)N * 128 * 2);  // reused as agg (f16)
  _Float16* qbuf = (_Float16*)alloc((size_t)N * 128 * 2);
  _Float16* kvi  = (_Float16*)alloc((size_t)N * 256 * 2);
  int* rperm     = (int*)alloc((size_t)E * 4);
  _Float16* Wc   = (_Float16*)alloc(384 * 128 * 2);
  _Float16* Wof  = (_Float16*)alloc(128 * 128 * 2);
  int* cnt       = (int*)alloc((size_t)(N + 1) * 4);
  int* offs      = (int*)alloc((size_t)(N + 1) * 4);
  int* cur       = (int*)alloc((size_t)N * 4);
  int* bsum      = (int*)alloc(64 * 4);

  const int nb = (N + 1023) / 1024;  // 49 for N=50000 (<=64 supported)

  build_weights<<<256, 256, 0, stream>>>(Wq, Wk, Wv, Wo, Wc, Wof);
  xtan_kernel<<<(N + 3) / 4, 256, 0, stream>>>(x, xtan, cnt, N);
  gemm_mfma<3, 0><<<(N + 63) / 64, 256, 0, stream>>>(xtan, Wc, qbuf, kvi, nullptr, N);
  count_kernel<<<(E + 255) / 256, 256, 0, stream>>>(col, cnt, E);
  scan_part<<<nb, 256, 0, stream>>>(cnt, bsum, N);
  scan_final<<<nb, 256, 0, stream>>>(cnt, bsum, offs, cur, N, nb);
  scatter_kernel<<<(E + 255) / 256, 256, 0, stream>>>(col, row, cur, rperm, E);
  attn_kernel<<<(N + 3) / 4, 256, 0, stream>>>(qbuf, (const f16x8*)kvi, rperm, offs, xtan, N);
  gemm_mfma<1, 1><<<(N + 63) / 64, 256, 0, stream>>>(xtan, Wof, out, nullptr, bo, N);
}